// Round 1
// baseline (50.636 us; speedup 1.0000x reference)
//
#include <hip/hip_runtime.h>

// out[i] = action_embed[i] . t[b(i)],  t = state_embed @ (wq @ wk^T),  b(i) = rev_idx[i]/20
//
// K1: M[d][e] = dot(wq[d,:], wk[e,:])          (128x128, tiny)
// K2: t = state @ M                             (f32 vector GEMM, 16384x128x128)
// K3: out[i] = dot(action[i,:], t[b,:])         (memory-bound, 105 MB read)

__global__ __launch_bounds__(256) void k1_weights(const float* __restrict__ wq,
                                                  const float* __restrict__ wk,
                                                  float* __restrict__ M) {
    int idx = blockIdx.x * 256 + threadIdx.x;    // 0..16383
    int d = idx >> 7, e = idx & 127;
    const float4* q4 = reinterpret_cast<const float4*>(wq + (size_t)d * 128);
    const float4* w4 = reinterpret_cast<const float4*>(wk + (size_t)e * 128);
    float acc = 0.f;
#pragma unroll
    for (int k = 0; k < 32; ++k) {
        float4 a = q4[k], b = w4[k];
        acc += a.x * b.x + a.y * b.y + a.z * b.z + a.w * b.w;
    }
    M[idx] = acc;
}

// K2: 128 rows/block, 256 threads, thread computes 8 rows x 8 cols.
// state tile in LDS, float-index swizzle fi ^= ((r>>3)&3)<<2 keeps b128 reads conflict-free.
__global__ __launch_bounds__(256) void k2_t(const float* __restrict__ state,
                                            const float* __restrict__ M,
                                            float* __restrict__ t) {
    __shared__ float sS[128 * 128];
    const int tid = threadIdx.x;
    const int row0 = blockIdx.x * 128;

#pragma unroll
    for (int it = 0; it < 16; ++it) {
        int f = it * 1024 + tid * 4;
        int r = f >> 7, d = f & 127;
        float4 v = *reinterpret_cast<const float4*>(state + (size_t)(row0 + r) * 128 + d);
        int fi = (r * 128 + d) ^ (((r >> 3) & 3) << 2);
        *reinterpret_cast<float4*>(sS + fi) = v;
    }
    __syncthreads();

    const int cg = tid & 15, rg = tid >> 4;
    const int c0 = cg * 8;
    const int r0 = rg * 8;

    float acc[8][8];
#pragma unroll
    for (int i = 0; i < 8; ++i)
#pragma unroll
        for (int j = 0; j < 8; ++j) acc[i][j] = 0.f;

    for (int k = 0; k < 32; ++k) {   // 4 d's per iteration
        float4 w[4][2];
#pragma unroll
        for (int dd = 0; dd < 4; ++dd) {
            int d = k * 4 + dd;
            w[dd][0] = *reinterpret_cast<const float4*>(M + (size_t)d * 128 + c0);
            w[dd][1] = *reinterpret_cast<const float4*>(M + (size_t)d * 128 + c0 + 4);
        }
#pragma unroll
        for (int i = 0; i < 8; ++i) {
            int r = r0 + i;
            int fi = (r * 128 + k * 4) ^ (((r >> 3) & 3) << 2);
            float4 s4 = *reinterpret_cast<const float4*>(sS + fi);
            float sv[4] = {s4.x, s4.y, s4.z, s4.w};
#pragma unroll
            for (int dd = 0; dd < 4; ++dd) {
                float s = sv[dd];
                acc[i][0] += s * w[dd][0].x;
                acc[i][1] += s * w[dd][0].y;
                acc[i][2] += s * w[dd][0].z;
                acc[i][3] += s * w[dd][0].w;
                acc[i][4] += s * w[dd][1].x;
                acc[i][5] += s * w[dd][1].y;
                acc[i][6] += s * w[dd][1].z;
                acc[i][7] += s * w[dd][1].w;
            }
        }
    }

#pragma unroll
    for (int i = 0; i < 8; ++i) {
        size_t r = (size_t)(row0 + r0 + i);
        float4 o0 = make_float4(acc[i][0], acc[i][1], acc[i][2], acc[i][3]);
        float4 o1 = make_float4(acc[i][4], acc[i][5], acc[i][6], acc[i][7]);
        *reinterpret_cast<float4*>(t + r * 128 + c0) = o0;
        *reinterpret_cast<float4*>(t + r * 128 + c0 + 4) = o1;
    }
}

// K3: 8 lanes per node; lane ln covers d = ln*4 + 32*i (i=0..3) -> per-instr the wave
// touches 8 contiguous 128B segments (full cache lines). shfl-xor reduce over 8 lanes.
__global__ __launch_bounds__(256) void k3_scores(const float* __restrict__ action,
                                                 const float* __restrict__ t,
                                                 const int* __restrict__ rev,
                                                 float* __restrict__ out,
                                                 int n_nodes) {
    int g = blockIdx.x * 256 + threadIdx.x;
    int node = g >> 3, ln = g & 7;
    if (node >= n_nodes) return;
    int b = rev[node] / 20;
    const float* arow = action + (size_t)node * 128;
    const float* trow = t + (size_t)b * 128;
    float acc = 0.f;
#pragma unroll
    for (int i = 0; i < 4; ++i) {
        int d = ln * 4 + i * 32;
        float4 a = *reinterpret_cast<const float4*>(arow + d);
        float4 x = *reinterpret_cast<const float4*>(trow + d);
        acc += a.x * x.x + a.y * x.y + a.z * x.z + a.w * x.w;
    }
    acc += __shfl_xor(acc, 1);
    acc += __shfl_xor(acc, 2);
    acc += __shfl_xor(acc, 4);
    if (ln == 0) out[node] = acc;
}

extern "C" void kernel_launch(void* const* d_in, const int* in_sizes, int n_in,
                              void* d_out, int out_size, void* d_ws, size_t ws_size,
                              hipStream_t stream) {
    const float* state  = (const float*)d_in[0];   // [B,128] f32
    const float* action = (const float*)d_in[1];   // [total,128] f32
    const float* wq     = (const float*)d_in[2];   // [128,128] f32
    const float* wk     = (const float*)d_in[3];   // [128,128] f32
    const int*   rev    = (const int*)d_in[6];     // [total] i32
    float* out = (float*)d_out;

    const int B = in_sizes[0] / 128;               // 16384
    const int n_nodes = in_sizes[6];               // 204800

    float* M = (float*)d_ws;                                   // 64 KB
    float* t = (float*)((char*)d_ws + 65536);                  // B*128*4 = 8.4 MB

    k1_weights<<<(128 * 128) / 256, 256, 0, stream>>>(wq, wk, M);
    k2_t<<<B / 128, 256, 0, stream>>>(state, M, t);
    k3_scores<<<(n_nodes * 8 + 255) / 256, 256, 0, stream>>>(action, t, rev, out, n_nodes);
}